// Round 3
// baseline (259.493 us; speedup 1.0000x reference)
//
#include <hip/hip_runtime.h>
#include <math.h>

namespace {

constexpr int Himg = 224, Wimg = 224, Cn = 3, Kk = 32;
constexpr int MAXT = 64;
constexpr int WSTRIDE = 512;               // ints per image in tap workspace
constexpr int IMG_F  = Himg * Wimg * Cn;   // 150528 floats per image
constexpr int ROW_F  = Wimg * Cn;          // 672 floats per row
constexpr int ROW_B  = ROW_F * 4;          // 2688 B

constexpr int IN_CH  = 144;                // interior chunk-cols: k in [12,156)
constexpr int ED_CH  = 24;                 // edge chunk-cols: k<12 or k>=156
constexpr int YG     = Himg / 4;           // 56 row-groups of 4 rows
constexpr int IN_IT  = YG * IN_CH;         // 8064 items/image (each = 4 rows x 1 chunk)
constexpr int ED_IT  = YG * ED_CH;         // 1344 items/image
constexpr int IN_BLK = (IN_IT + 255) / 256;   // 32 (last block part-masked)
constexpr int ED_BLK = (ED_IT + 255) / 256;   // 6  (last block part-masked)
constexpr int BLK_PER_IMG = IN_BLK + ED_BLK;  // 38

typedef float v4  __attribute__((ext_vector_type(4), aligned(4)));
typedef float v4a __attribute__((ext_vector_type(4), aligned(16)));

// ws per-image layout (ints): [0]=n  [1]=w  [2..65]=dky  [66..129]=dkx  [130..193]=xoff(bytes)

// ---------------- pre-pass: one tap list per image ----------------
__global__ __launch_bounds__(64)
void build_taps(const float* __restrict__ tbl,
                const int* __restrict__ amt,
                const int* __restrict__ ang,
                int* __restrict__ ws)
{
    const int b   = blockIdx.x;
    const int tid = threadIdx.x;

    __shared__ int   s_cnt;
    __shared__ float s_w;
    __shared__ int   s_dky[MAXT], s_dkx[MAXT];

    if (tid == 0) { s_cnt = 0; s_w = 0.0f; }
    __syncthreads();

    const int a = amt[b];
    // reference-exact numerics (verified absmax 0.0039 across all prior rounds)
    const float  rad = (float)ang[b] * (float)(M_PI / 180.0);
    const double rd  = (double)rad;
    const float  cth = (float)cos(rd);
    const float  sth = (float)sin(rd);
    const float  e   = 31.0f;
    const float xoff = __fmul_rn(__fsub_rn(e, __fsub_rn(__fmul_rn(cth, e), __fmul_rn(sth, e))), 0.5f);
    const float yoff = __fmul_rn(__fsub_rn(e, __fadd_rn(__fmul_rn(sth, e), __fmul_rn(cth, e))), 0.5f);

    for (int p = tid; p < Kk * Kk; p += 64) {
        const int   ky = p >> 5, kx = p & 31;
        const float xf = (float)kx, yf = (float)ky;
        const float sx = __fadd_rn(__fsub_rn(__fmul_rn(cth, xf), __fmul_rn(sth, yf)), xoff);
        const float sy = __fadd_rn(__fadd_rn(__fmul_rn(sth, xf), __fmul_rn(cth, yf)), yoff);
        const int ix = (int)rintf(sx);   // round-half-even == jnp.round
        const int iy = (int)rintf(sy);
        if (ix >= 0 && ix < Kk && iy >= 0 && iy < Kk) {
            const float v = tbl[((a * Kk + iy) * Kk + ix) * Cn];
            if (v != 0.0f) {
                const int idx = atomicAdd(&s_cnt, 1);
                if (idx < MAXT) {
                    s_dky[idx] = ky - 15;
                    s_dkx[idx] = kx - 15;
                    s_w = v;                 // benign race: all writers store 1/size
                }
            }
        }
    }
    __syncthreads();

    const int n = min(s_cnt, MAXT);
    int* wsb = ws + b * WSTRIDE;
    if (tid == 0) { wsb[0] = n; wsb[1] = __float_as_int(s_w); }
    for (int i = tid; i < n; i += 64) {
        wsb[2 + i]   = s_dky[i];
        wsb[66 + i]  = s_dkx[i];
        wsb[130 + i] = s_dky[i] * ROW_B + s_dkx[i] * (int)(Cn * sizeof(float));
    }
}

// ---------------- conv, 4-row register blocking ----------------
// Each thread computes 4 vertically-adjacent output chunks (rows y0..y0+3, same
// chunk-col). Per tap: 4 loads into 4 DISTINCT accumulators -> the scheduler
// cannot collapse them into one register (R1/R2 showed it serializes unrolled
// loads feeding a single acc chain; VGPR stayed 40). MLP is now in the dataflow.
__global__ __launch_bounds__(256, 2)
void blur_rb4(const float* __restrict__ x,
              const int* __restrict__ ws,
              float* __restrict__ out,
              int B)
{
    const int tid = threadIdx.x;
    const int L   = blockIdx.x;

    // XCD-pinned decode: image b handled entirely by XCD (b & 7).
    int b, c;
    if (B == 128) {
        const int xcd = L & 7;
        const int j   = L >> 3;                 // [0, 16*38)
        const int g   = j / BLK_PER_IMG;
        c = j - g * BLK_PER_IMG;
        b = g * 8 + xcd;
    } else {
        b = L / BLK_PER_IMG;
        c = L - b * BLK_PER_IMG;
    }

    __shared__ int shNW[2];
    __shared__ int s_dky[MAXT], s_dkx[MAXT], s_xoff[MAXT];
    const int* wsb = ws + b * WSTRIDE;
    if (tid < 2)    shNW[tid]   = wsb[tid];
    if (tid < MAXT) {
        s_dky[tid]  = wsb[2 + tid];
        s_dkx[tid]  = wsb[66 + tid];
        s_xoff[tid] = wsb[130 + tid];
    }
    __syncthreads();

    const int   n = shNW[0];
    const float w = __int_as_float(shNW[1]);
    const float* xb = x + (size_t)b * IMG_F;

    if (c < IN_BLK) {
        // ---- interior: 4 rows x 1 chunk-col per thread, dwordx4 per row ----
        const int idx = c * 256 + tid;
        if (idx >= IN_IT) return;               // pad tail of last block
        const int y4 = idx / IN_CH;
        const int kk = idx - y4 * IN_CH;
        const int k  = kk + 12;                 // [12, 156)
        const int y0 = y4 * 4;
        const int fbase = y0 * ROW_F + 4 * k;
        const char* base = (const char*)xb + (size_t)fbase * 4;   // row y0, own chunk

        v4 acc0 = {0,0,0,0}, acc1 = {0,0,0,0}, acc2 = {0,0,0,0}, acc3 = {0,0,0,0};

        // fast path: rows y0-15 .. y0+3+16 all within [0,224): y4 in [4,52)
        if (y4 >= 4 && y4 < 52) {
            for (int i = 0; i < n; ++i) {
                const int off = s_xoff[i];
                const v4 f0 = *(const v4*)(base + off);
                const v4 f1 = *(const v4*)(base + off + ROW_B);
                const v4 f2 = *(const v4*)(base + off + 2 * ROW_B);
                const v4 f3 = *(const v4*)(base + off + 3 * ROW_B);
                acc0 += f0; acc1 += f1; acc2 += f2; acc3 += f3;   // tap-ascending per output
            }
        } else {
            // y-edge: per-row mask, branchless; base+0 (own chunk, row y0) is safe
            for (int i = 0; i < n; ++i) {
                const int off = s_xoff[i];
                const int r0  = y0 + s_dky[i];
                const bool ok0 = (unsigned)(r0)     < (unsigned)Himg;
                const bool ok1 = (unsigned)(r0 + 1) < (unsigned)Himg;
                const bool ok2 = (unsigned)(r0 + 2) < (unsigned)Himg;
                const bool ok3 = (unsigned)(r0 + 3) < (unsigned)Himg;
                const v4 f0 = *(const v4*)(base + (ok0 ? off             : 0));
                const v4 f1 = *(const v4*)(base + (ok1 ? off +     ROW_B : 0));
                const v4 f2 = *(const v4*)(base + (ok2 ? off + 2 * ROW_B : 0));
                const v4 f3 = *(const v4*)(base + (ok3 ? off + 3 * ROW_B : 0));
                const float m0 = ok0 ? 1.0f : 0.0f;
                const float m1 = ok1 ? 1.0f : 0.0f;
                const float m2 = ok2 ? 1.0f : 0.0f;
                const float m3 = ok3 ? 1.0f : 0.0f;
                acc0 += m0 * f0; acc1 += m1 * f1; acc2 += m2 * f2; acc3 += m3 * f3;
            }
        }

        float* o = out + (size_t)b * IMG_F + fbase;
        __builtin_nontemporal_store(v4a{acc0.x * w, acc0.y * w, acc0.z * w, acc0.w * w}, (v4a*)o);
        __builtin_nontemporal_store(v4a{acc1.x * w, acc1.y * w, acc1.z * w, acc1.w * w}, (v4a*)(o + ROW_F));
        __builtin_nontemporal_store(v4a{acc2.x * w, acc2.y * w, acc2.z * w, acc2.w * w}, (v4a*)(o + 2 * ROW_F));
        __builtin_nontemporal_store(v4a{acc3.x * w, acc3.y * w, acc3.z * w, acc3.w * w}, (v4a*)(o + 3 * ROW_F));
    } else {
        // ---- x-edge: 4 rows per thread, masked scalar loads (16 indep loads/tap) ----
        const int e = (c - IN_BLK) * 256 + tid;
        if (e >= ED_IT) return;
        const int y4 = e / ED_CH;
        const int j  = e - y4 * ED_CH;
        const int k  = (j < 12) ? j : (j + 144);   // [0,12) U [156,168)
        const int fd0 = 4 * k;
        const int y0  = 4 * y4;

        float acc[4][4] = {};
        for (int i = 0; i < n; ++i) {
            const int s0 = fd0 + 3 * s_dkx[i];
            const int r0 = y0 + s_dky[i];
#pragma unroll
            for (int q = 0; q < 4; ++q) {
                const int  row = r0 + q;
                const bool rok = (unsigned)row < (unsigned)Himg;
                const int  ob  = row * ROW_F + s0;
#pragma unroll
                for (int ch = 0; ch < 4; ++ch) {
                    const bool ok  = rok & ((unsigned)(s0 + ch) < (unsigned)ROW_F);
                    const float v = xb[ok ? (ob + ch) : 0];
                    acc[q][ch] += ok ? v : 0.0f;
                }
            }
        }

        float* o = out + (size_t)b * IMG_F + (size_t)y0 * ROW_F + fd0;
#pragma unroll
        for (int q = 0; q < 4; ++q) {
            __builtin_nontemporal_store(
                v4a{acc[q][0] * w, acc[q][1] * w, acc[q][2] * w, acc[q][3] * w},
                (v4a*)(o + q * ROW_F));
        }
    }
}

}  // namespace

extern "C" void kernel_launch(void* const* d_in, const int* in_sizes, int n_in,
                              void* d_out, int out_size, void* d_ws, size_t ws_size,
                              hipStream_t stream) {
    const float* x   = (const float*)d_in[0];
    const float* tbl = (const float*)d_in[1];
    const int*   amt = (const int*)d_in[2];
    const int*   ang = (const int*)d_in[3];
    float*       out = (float*)d_out;
    int*         ws  = (int*)d_ws;

    const int B = in_sizes[2];  // 128

    build_taps<<<B, 64, 0, stream>>>(tbl, amt, ang, ws);
    blur_rb4<<<B * BLK_PER_IMG, 256, 0, stream>>>(x, ws, out, B);
}

// Round 4
// 235.009 us; speedup vs baseline: 1.1042x; 1.1042x over previous
//
#include <hip/hip_runtime.h>
#include <math.h>

namespace {

constexpr int Himg = 224, Wimg = 224, Cn = 3, Kk = 32;
constexpr int MAXT = 64;
constexpr int WSTRIDE = 512;               // ints per image in tap workspace
constexpr int IMG_F  = Himg * Wimg * Cn;   // 150528 floats per image
constexpr int ROW_F  = Wimg * Cn;          // 672 floats per row (== 0 mod 4)
constexpr int ROW_B  = ROW_F * 4;          // 2688 B

constexpr int IN_CH  = 144;                // interior chunk-cols: k in [12,156)
constexpr int ED_CH  = 24;                 // edge chunk-cols: k<12 or k>=156
constexpr int IN_PER_IMG = Himg * IN_CH;   // 32256
constexpr int ED_PER_IMG = Himg * ED_CH;   // 5376
constexpr int IN_BLK = IN_PER_IMG / 256;   // 126
constexpr int ED_BLK = ED_PER_IMG / 256;   // 21
constexpr int BLK_PER_IMG = IN_BLK + ED_BLK;  // 147
// interior blocks c in [9,117) have all rows y in [16,208) -> no vertical mask
constexpr int FAST_LO = 9, FAST_HI = 117;

typedef float v4  __attribute__((ext_vector_type(4), aligned(4)));
typedef float v4a __attribute__((ext_vector_type(4), aligned(16)));

// ws per-image layout (ints): [0]=n  [1]=w  [2..65]=dky  [66..129]=dkx  [130..193]=xoff(bytes)

// ---------------- pre-pass: one tap list per image ----------------
__global__ __launch_bounds__(64)
void build_taps(const float* __restrict__ tbl,
                const int* __restrict__ amt,
                const int* __restrict__ ang,
                int* __restrict__ ws)
{
    const int b   = blockIdx.x;
    const int tid = threadIdx.x;

    __shared__ int   s_cnt;
    __shared__ float s_w;
    __shared__ int   s_dky[MAXT], s_dkx[MAXT];

    if (tid == 0) { s_cnt = 0; s_w = 0.0f; }
    __syncthreads();

    const int a = amt[b];
    // reference-exact numerics (verified absmax 0.0039 across all prior rounds)
    const float  rad = (float)ang[b] * (float)(M_PI / 180.0);
    const double rd  = (double)rad;
    const float  cth = (float)cos(rd);
    const float  sth = (float)sin(rd);
    const float  e   = 31.0f;
    const float xoff = __fmul_rn(__fsub_rn(e, __fsub_rn(__fmul_rn(cth, e), __fmul_rn(sth, e))), 0.5f);
    const float yoff = __fmul_rn(__fsub_rn(e, __fadd_rn(__fmul_rn(sth, e), __fmul_rn(cth, e))), 0.5f);

    for (int p = tid; p < Kk * Kk; p += 64) {
        const int   ky = p >> 5, kx = p & 31;
        const float xf = (float)kx, yf = (float)ky;
        const float sx = __fadd_rn(__fsub_rn(__fmul_rn(cth, xf), __fmul_rn(sth, yf)), xoff);
        const float sy = __fadd_rn(__fadd_rn(__fmul_rn(sth, xf), __fmul_rn(cth, yf)), yoff);
        const int ix = (int)rintf(sx);   // round-half-even == jnp.round
        const int iy = (int)rintf(sy);
        if (ix >= 0 && ix < Kk && iy >= 0 && iy < Kk) {
            const float v = tbl[((a * Kk + iy) * Kk + ix) * Cn];
            if (v != 0.0f) {
                const int idx = atomicAdd(&s_cnt, 1);
                if (idx < MAXT) {
                    s_dky[idx] = ky - 15;
                    s_dkx[idx] = kx - 15;
                    s_w = v;                 // benign race: all writers store 1/size
                }
            }
        }
    }
    __syncthreads();

    const int n = min(s_cnt, MAXT);
    int* wsb = ws + b * WSTRIDE;
    if (tid == 0) { wsb[0] = n; wsb[1] = __float_as_int(s_w); }
    for (int i = tid; i < n; i += 64) {
        wsb[2 + i]   = s_dky[i];
        wsb[66 + i]  = s_dkx[i];
        wsb[130 + i] = s_dky[i] * ROW_B + s_dkx[i] * (int)(Cn * sizeof(float));
    }
}

// ---------------- conv, R2 structure + independent accumulator chains ----------------
// R3 evidence: 4 loads feeding 4 DISTINCT accumulators -> ~3x per-wave MLP
// (waves/4 cost only 1.37x time). A single serial add chain (R1) pins loads to
// consume-in-order and the allocator recycles payload regs (VGPR stuck at 40).
// Here: R2's wave count (maximal TLP) + 8 independent chains (per-wave MLP).
// Tap regrouping is numerically safe: tap order is already atomicAdd-scrambled.
__global__ __launch_bounds__(256, 2)
void blur_direct(const float* __restrict__ x,
                 const int* __restrict__ ws,
                 float* __restrict__ out,
                 int B)
{
    const int tid = threadIdx.x;
    const int L   = blockIdx.x;

    // XCD-pinned decode: image b handled entirely by XCD (b & 7).
    int b, c;
    if (B == 128) {
        const int xcd = L & 7;
        const int j   = L >> 3;                 // [0, 16*147)
        const int g   = j / BLK_PER_IMG;
        c = j - g * BLK_PER_IMG;
        b = g * 8 + xcd;
    } else {
        b = L / BLK_PER_IMG;
        c = L - b * BLK_PER_IMG;
    }

    __shared__ int shNW[2];
    __shared__ int s_dky[MAXT], s_dkx[MAXT], s_xoff[MAXT];
    const int* wsb = ws + b * WSTRIDE;
    if (tid < 2)    shNW[tid]   = wsb[tid];
    if (tid < MAXT) {
        s_dky[tid]  = wsb[2 + tid];
        s_dkx[tid]  = wsb[66 + tid];
        s_xoff[tid] = wsb[130 + tid];
    }
    __syncthreads();

    const int   n = shNW[0];
    const float w = __int_as_float(shNW[1]);
    const float* xb = x + (size_t)b * IMG_F;

    if (c < IN_BLK) {
        // ---- interior chunk-columns: contiguous dwordx4 per tap ----
        const int ii = c * 256 + tid;
        const int y  = ii / IN_CH;
        const int k  = ii - y * IN_CH + 12;     // [12, 156)
        const int fbase = y * ROW_F + 4 * k;
        const char* base = (const char*)xb + (size_t)fbase * 4;

        v4 S;

        if (c >= FAST_LO && c < FAST_HI) {
            // fast path: 8 independent accumulator chains -> 8 loads in flight
            v4 A0 = {0,0,0,0}, A1 = {0,0,0,0}, A2 = {0,0,0,0}, A3 = {0,0,0,0};
            v4 A4 = {0,0,0,0}, A5 = {0,0,0,0}, A6 = {0,0,0,0}, A7 = {0,0,0,0};
            int i = 0;
            for (; i + 8 <= n; i += 8) {
                const v4 f0 = *(const v4*)(base + s_xoff[i]);
                const v4 f1 = *(const v4*)(base + s_xoff[i + 1]);
                const v4 f2 = *(const v4*)(base + s_xoff[i + 2]);
                const v4 f3 = *(const v4*)(base + s_xoff[i + 3]);
                const v4 f4 = *(const v4*)(base + s_xoff[i + 4]);
                const v4 f5 = *(const v4*)(base + s_xoff[i + 5]);
                const v4 f6 = *(const v4*)(base + s_xoff[i + 6]);
                const v4 f7 = *(const v4*)(base + s_xoff[i + 7]);
                A0 += f0; A1 += f1; A2 += f2; A3 += f3;
                A4 += f4; A5 += f5; A6 += f6; A7 += f7;
            }
            if (i + 4 <= n) {
                const v4 f0 = *(const v4*)(base + s_xoff[i]);
                const v4 f1 = *(const v4*)(base + s_xoff[i + 1]);
                const v4 f2 = *(const v4*)(base + s_xoff[i + 2]);
                const v4 f3 = *(const v4*)(base + s_xoff[i + 3]);
                A0 += f0; A1 += f1; A2 += f2; A3 += f3;
                i += 4;
            }
            for (; i < n; ++i) A0 += *(const v4*)(base + s_xoff[i]);
            S = ((A0 + A1) + (A2 + A3)) + ((A4 + A5) + (A6 + A7));
        } else {
            // y-edge blocks: 4 independent masked chains
            v4 A0 = {0,0,0,0}, A1 = {0,0,0,0}, A2 = {0,0,0,0}, A3 = {0,0,0,0};
            int i = 0;
            for (; i + 4 <= n; i += 4) {
                const int  r0 = y + s_dky[i];     const bool ok0 = (unsigned)r0 < (unsigned)Himg;
                const int  r1 = y + s_dky[i + 1]; const bool ok1 = (unsigned)r1 < (unsigned)Himg;
                const int  r2 = y + s_dky[i + 2]; const bool ok2 = (unsigned)r2 < (unsigned)Himg;
                const int  r3 = y + s_dky[i + 3]; const bool ok3 = (unsigned)r3 < (unsigned)Himg;
                const v4 f0 = *(const v4*)(base + (ok0 ? s_xoff[i]     : 0));
                const v4 f1 = *(const v4*)(base + (ok1 ? s_xoff[i + 1] : 0));
                const v4 f2 = *(const v4*)(base + (ok2 ? s_xoff[i + 2] : 0));
                const v4 f3 = *(const v4*)(base + (ok3 ? s_xoff[i + 3] : 0));
                const float m0 = ok0 ? 1.0f : 0.0f;
                const float m1 = ok1 ? 1.0f : 0.0f;
                const float m2 = ok2 ? 1.0f : 0.0f;
                const float m3 = ok3 ? 1.0f : 0.0f;
                A0 += m0 * f0; A1 += m1 * f1; A2 += m2 * f2; A3 += m3 * f3;
            }
            for (; i < n; ++i) {
                const int  row = y + s_dky[i];
                const bool ok  = (unsigned)row < (unsigned)Himg;
                const int  off = ok ? s_xoff[i] : 0;      // base+0 = own chunk (in-bounds)
                const float m  = ok ? 1.0f : 0.0f;
                const v4 f = *(const v4*)(base + off);
                A0 += m * f;
            }
            S = (A0 + A1) + (A2 + A3);
        }

        float* o = out + (size_t)b * IMG_F + fbase;
        __builtin_nontemporal_store(v4a{S.x * w, S.y * w, S.z * w, S.w * w}, (v4a*)o);
    } else {
        // ---- x-edge chunk-columns: masked scalar loads, 2 independent chain-sets ----
        const int ee = (c - IN_BLK) * 256 + tid;
        const int y  = ee / ED_CH;
        const int j  = ee - y * ED_CH;
        const int k  = (j < 12) ? j : (j + 144);   // [0,12) U [156,168)
        const int fd0 = 4 * k;

        float accA[4] = {0.0f, 0.0f, 0.0f, 0.0f};
        float accB[4] = {0.0f, 0.0f, 0.0f, 0.0f};
        int i = 0;
        for (; i + 2 <= n; i += 2) {
            const int  r0  = y + s_dky[i];
            const int  r1  = y + s_dky[i + 1];
            const bool rk0 = (unsigned)r0 < (unsigned)Himg;
            const bool rk1 = (unsigned)r1 < (unsigned)Himg;
            const int  s00 = fd0 + 3 * s_dkx[i];
            const int  s01 = fd0 + 3 * s_dkx[i + 1];
            const int  ob0 = r0 * ROW_F + s00;
            const int  ob1 = r1 * ROW_F + s01;
#pragma unroll
            for (int q = 0; q < 4; ++q) {
                const bool ok0 = rk0 & ((unsigned)(s00 + q) < (unsigned)ROW_F);
                const bool ok1 = rk1 & ((unsigned)(s01 + q) < (unsigned)ROW_F);
                const float u0 = xb[ok0 ? (ob0 + q) : 0];
                const float u1 = xb[ok1 ? (ob1 + q) : 0];
                accA[q] += ok0 ? u0 : 0.0f;   // even taps -> accA, odd -> accB (indep chains)
                accB[q] += ok1 ? u1 : 0.0f;
            }
        }
        for (; i < n; ++i) {
            const int  row = y + s_dky[i];
            const bool rok = (unsigned)row < (unsigned)Himg;
            const int  s0  = fd0 + 3 * s_dkx[i];
            const int  ob  = row * ROW_F + s0;
#pragma unroll
            for (int q = 0; q < 4; ++q) {
                const bool ok  = rok & ((unsigned)(s0 + q) < (unsigned)ROW_F);
                const int  off = ok ? (ob + q) : 0;
                const float v  = xb[off];
                accA[q] += ok ? v : 0.0f;
            }
        }

        float* o = out + (size_t)b * IMG_F + (size_t)y * ROW_F + fd0;
        __builtin_nontemporal_store(
            v4a{(accA[0] + accB[0]) * w, (accA[1] + accB[1]) * w,
                (accA[2] + accB[2]) * w, (accA[3] + accB[3]) * w}, (v4a*)o);
    }
}

}  // namespace

extern "C" void kernel_launch(void* const* d_in, const int* in_sizes, int n_in,
                              void* d_out, int out_size, void* d_ws, size_t ws_size,
                              hipStream_t stream) {
    const float* x   = (const float*)d_in[0];
    const float* tbl = (const float*)d_in[1];
    const int*   amt = (const int*)d_in[2];
    const int*   ang = (const int*)d_in[3];
    float*       out = (float*)d_out;
    int*         ws  = (int*)d_ws;

    const int B = in_sizes[2];  // 128

    build_taps<<<B, 64, 0, stream>>>(tbl, amt, ang, ws);
    blur_direct<<<B * BLK_PER_IMG, 256, 0, stream>>>(x, ws, out, B);
}